// Round 3
// baseline (307.190 us; speedup 1.0000x reference)
//
#include <hip/hip_runtime.h>
#include <math.h>

typedef __attribute__((ext_vector_type(8))) short short8;
typedef __attribute__((ext_vector_type(4))) float f32x4;

#define B_SZ 8192
#define D_INN 4000
#define EMBD 96
#define H0D 2048
#define H1D 1024
#define KDIM 4096  // EMB + D_IN

__device__ __forceinline__ unsigned short f2bf(float f) {
  union { float f; unsigned u; } v; v.f = f;
  unsigned r = v.u + 0x7FFFu + ((v.u >> 16) & 1u);
  return (unsigned short)(r >> 16);
}
__device__ __forceinline__ float bf2f(unsigned short h) {
  union { unsigned u; float f; } v; v.u = ((unsigned)h) << 16;
  return v.f;
}
__device__ __forceinline__ void gld_lds16(const void* g, void* l) {
  __builtin_amdgcn_global_load_lds(
      (const __attribute__((address_space(1))) unsigned int*)g,
      (__attribute__((address_space(3))) unsigned int*)l, 16, 0, 0);
}

// ---- transpose + fp32->bf16 convert: out[c][r] = bf16(in[r][c]) ----
__global__ __launch_bounds__(256) void transpose_cvt(
    const float* __restrict__ in, unsigned short* __restrict__ out, int R, int C) {
  __shared__ float tile[32][33];
  int c0 = blockIdx.x * 32, r0 = blockIdx.y * 32;
  int tc = threadIdx.x & 31, tr = threadIdx.x >> 5;
#pragma unroll
  for (int i = 0; i < 4; ++i) {
    int r = tr + i * 8;
    tile[r][tc] = in[(size_t)(r0 + r) * C + (c0 + tc)];
  }
  __syncthreads();
#pragma unroll
  for (int i = 0; i < 4; ++i) {
    int rr = tr + i * 8;
    out[(size_t)(c0 + rr) * R + (r0 + tc)] = f2bf(tile[tc][rr]);
  }
}

// ---- build A = [emb_gather | inputs] in bf16, vectorized 8-wide ----
__global__ __launch_bounds__(256) void build_A(
    const float* __restrict__ inputs, const float* __restrict__ emb,
    const int* __restrict__ ballot, const int* __restrict__ contest,
    unsigned short* __restrict__ A) {
  int gid = blockIdx.x * 256 + threadIdx.x;   // chunk of 8 elems
  int b = gid >> 9, c = gid & 511;            // 512 chunks per row of 4096
  const float* src;
  if (c < EMBD / 8) {
    int e = ballot[b] * 8 + contest[b];
    src = emb + (size_t)e * EMBD + c * 8;
  } else {
    src = inputs + (size_t)b * D_INN + (c - EMBD / 8) * 8;
  }
  float4 v0 = *(const float4*)src;
  float4 v1 = *(const float4*)(src + 4);
  unsigned short r[8];
  r[0] = f2bf(v0.x); r[1] = f2bf(v0.y); r[2] = f2bf(v0.z); r[3] = f2bf(v0.w);
  r[4] = f2bf(v1.x); r[5] = f2bf(v1.y); r[6] = f2bf(v1.z); r[7] = f2bf(v1.w);
  *reinterpret_cast<short8*>(A + (size_t)b * KDIM + c * 8) =
      *reinterpret_cast<const short8*>(r);
}

// ---- NT bf16 MFMA GEMM, ring-3, counted vmcnt, 2 blocks/CU desync ----
// 256 threads = 4 waves (WM x WN). Tile BM x BN, BK = 32.
// Ring-3 LDS; stage t+2 while computing t; one barrier per tile; MFMA
// cluster BEFORE the vmcnt+barrier so pipe drain overlaps the wait.
// 2 blocks/CU (LDS <= 72 KB) desync the per-SIMD wave pair so one block's
// MFMA burst fills the other block's read/wait window (m114 overlap).
template <int BM, int BN, int WM, int WN>
__global__ __launch_bounds__(256, 2) void gemm_nt_pipe(
    const unsigned short* __restrict__ A, const unsigned short* __restrict__ Bt,
    const float* __restrict__ bias, unsigned short* __restrict__ C,
    int K, int N, int NBN) {
  constexpr int MREP = BM / (WM * 16);
  constexpr int NREP = BN / (WN * 16);
  constexpr int AR = BM / 64, BR = BN / 64;   // 4KB stage rounds per tile
  constexpr int NLD = AR + BR;                // gld per thread per tile
  constexpr int AB = BM * 64, BB = BN * 64;   // slot bytes
  __shared__ char lds[3 * (AB + BB)];

  const int tid = threadIdx.x;
  const int w = tid >> 6, l = tid & 63;
  const int lr = l & 15, kg = l >> 4;
  const int wm = w / WN, wn = w % WN;

  // XCD-aware swizzle (gridDim.x % 8 == 0): each XCD gets contiguous swz
  int swz = (blockIdx.x & 7) * ((int)gridDim.x >> 3) + ((int)blockIdx.x >> 3);
  const int bm = swz / NBN, bn = swz - bm * NBN;
  const int NT = K >> 5;

  // staging source (pre-swizzled 16B slot; LDS dest stays linear)
  const int rg = l >> 2;
  const int sl = ((l & 3) ^ ((l >> 3) & 3)) * 8;
  const unsigned short* gaB = A + (size_t)(bm * BM + w * 16 + rg) * K + sl;
  const unsigned short* gbB = Bt + (size_t)(bn * BN + w * 16 + rg) * K + sl;

  // frag-read byte offsets (swizzled, verified conflict-free)
  const int xo = (kg ^ ((lr >> 1) & 3)) << 4;
  const int aoff = (wm * (MREP * 16) + lr) * 64 + xo;
  const int boff = (wn * (NREP * 16) + lr) * 64 + xo;

  f32x4 acc[MREP][NREP] = {};

  auto stage = [&](int t, int slot) {
    char* la = lds + slot * AB + w * 1024;            // wave-uniform dest
    char* lb = lds + 3 * AB + slot * BB + w * 1024;
    const size_t ko = (size_t)t * 32;
#pragma unroll
    for (int i = 0; i < AR; ++i)
      gld_lds16(gaB + (size_t)i * 64 * K + ko, la + i * 4096);
#pragma unroll
    for (int j = 0; j < BR; ++j)
      gld_lds16(gbB + (size_t)j * 64 * K + ko, lb + j * 4096);
  };

#define WAIT_STEADY() do { \
    if constexpr (NLD == 6) asm volatile("s_waitcnt vmcnt(6)" ::: "memory"); \
    else                    asm volatile("s_waitcnt vmcnt(4)" ::: "memory"); \
  } while (0)

  stage(0, 0);
  stage(1, 1);
  WAIT_STEADY();                       // tile 0 landed; tile 1 in flight
  __builtin_amdgcn_s_barrier();
  __builtin_amdgcn_sched_barrier(0);

  int rb = 0;
  for (int t = 0; t < NT; ++t) {
    int rb2 = rb + 2; if (rb2 >= 3) rb2 -= 3;
    const char* pa = lds + rb * AB + aoff;
    const char* pb = lds + 3 * AB + rb * BB + boff;
    short8 af[MREP], bfr[NREP];
#pragma unroll
    for (int mi = 0; mi < MREP; ++mi) af[mi] = *(const short8*)(pa + mi * 1024);
#pragma unroll
    for (int ni = 0; ni < NREP; ++ni) bfr[ni] = *(const short8*)(pb + ni * 1024);
    if (t + 2 < NT) stage(t + 2, rb2);  // overwrites slot of tile t-1 (reads
                                        // retired before prev barrier)
    asm volatile("s_waitcnt lgkmcnt(0)" ::: "memory");
    __builtin_amdgcn_sched_barrier(0);  // rule #18: pin MFMA after the wait
    __builtin_amdgcn_s_setprio(1);
#pragma unroll
    for (int mi = 0; mi < MREP; ++mi)
#pragma unroll
      for (int ni = 0; ni < NREP; ++ni)
        acc[mi][ni] = __builtin_amdgcn_mfma_f32_16x16x32_bf16(
            af[mi], bfr[ni], acc[mi][ni], 0, 0, 0);
    __builtin_amdgcn_s_setprio(0);
    __builtin_amdgcn_sched_barrier(0);
    if (t + 2 < NT) {
      WAIT_STEADY();                    // tile t+1 landed; t+2 in flight
      __builtin_amdgcn_s_barrier();
    } else if (t + 1 < NT) {
      asm volatile("s_waitcnt vmcnt(0)" ::: "memory");
      __builtin_amdgcn_s_barrier();
    }
    __builtin_amdgcn_sched_barrier(0);
    rb = rb + 1; if (rb >= 3) rb = 0;
  }

  // epilogue: bias + relu + bf16 store.  D: col=lane&15, row=(lane>>4)*4+j
#pragma unroll
  for (int mi = 0; mi < MREP; ++mi) {
    const int row0 = bm * BM + wm * (MREP * 16) + mi * 16 + kg * 4;
#pragma unroll
    for (int ni = 0; ni < NREP; ++ni) {
      const int col = bn * BN + wn * (NREP * 16) + ni * 16 + lr;
      const float bv = bias[col];
#pragma unroll
      for (int j = 0; j < 4; ++j) {
        float v = acc[mi][ni][j] + bv;
        v = v > 0.f ? v : 0.f;
        C[(size_t)(row0 + j) * N + col] = f2bf(v);
      }
    }
  }
#undef WAIT_STEADY
}

// ---- routed expert head, bucketed: 64 experts x 4 sample-range quarters ----
// Block (e,q) scans samples [q*2048,(q+1)*2048), collects matches in LDS,
// stages 32 h1 rows at a time (bf16, padded stride 1032 -> conflict-free
// broadcast reads), computes out = sigmoid(h1 . We[e] + be[e]) with float4
// We loads (We[e] is 131 KB, L2-resident; read ~4x total instead of 8192x).
__global__ __launch_bounds__(256) void expert_head_bucketed(
    const unsigned short* __restrict__ h1, const float* __restrict__ We,
    const float* __restrict__ be, const int* __restrict__ ballot,
    const int* __restrict__ contest, float* __restrict__ out) {
  const int e = blockIdx.x >> 2, q = blockIdx.x & 3;
  __shared__ unsigned short sidx[2048];
  __shared__ int scnt;
  __shared__ unsigned short sh1[32][1032];   // padded row: 2064 B (16B-aligned)
  if (threadIdx.x == 0) scnt = 0;
  __syncthreads();
  const int base = q * 2048;
  for (int i = threadIdx.x; i < 2048; i += 256) {
    int s = base + i;
    if (ballot[s] * 8 + contest[s] == e)
      sidx[atomicAdd(&scnt, 1)] = (unsigned short)s;
  }
  __syncthreads();
  const int cnt = scnt;
  const int so = threadIdx.x >> 3;   // sample slot 0..31
  const int oq = threadIdx.x & 7;    // float4 group over 32 outputs
  const float4* We4 = (const float4*)(We + (size_t)e * H1D * 32);
  for (int c0 = 0; c0 < cnt; c0 += 32) {
    const int ns = min(32, cnt - c0);
    __syncthreads();   // protect sh1 from previous chunk's readers
    for (int t = threadIdx.x; t < ns * 128; t += 256) {   // 128 short8 per row
      int r = t >> 7, cc = (t & 127) * 8;
      *(short8*)&sh1[r][cc] =
          *(const short8*)&h1[(size_t)sidx[c0 + r] * H1D + cc];
    }
    __syncthreads();
    if (so < ns) {
      const int s = sidx[c0 + so];
      float ax = 0.f, ay = 0.f, az = 0.f, aw = 0.f;
#pragma unroll 8
      for (int d = 0; d < H1D; ++d) {
        float h = bf2f(sh1[so][d]);
        float4 wv = We4[d * 8 + oq];
        ax = fmaf(h, wv.x, ax); ay = fmaf(h, wv.y, ay);
        az = fmaf(h, wv.z, az); aw = fmaf(h, wv.w, aw);
      }
      float4 bb = *(const float4*)&be[e * 32 + oq * 4];
      float4 r;
      r.x = 1.f / (1.f + expf(-(ax + bb.x)));
      r.y = 1.f / (1.f + expf(-(ay + bb.y)));
      r.z = 1.f / (1.f + expf(-(az + bb.z)));
      r.w = 1.f / (1.f + expf(-(aw + bb.w)));
      *(float4*)&out[(size_t)s * 32 + oq * 4] = r;
    }
  }
}

extern "C" void kernel_launch(void* const* d_in, const int* in_sizes, int n_in,
                              void* d_out, int out_size, void* d_ws, size_t ws_size,
                              hipStream_t stream) {
  const float* inputs = (const float*)d_in[0];
  const float* emb    = (const float*)d_in[1];
  const float* W0     = (const float*)d_in[2];
  const float* b0     = (const float*)d_in[3];
  const float* W1     = (const float*)d_in[4];
  const float* b1     = (const float*)d_in[5];
  const float* We     = (const float*)d_in[6];
  const float* be     = (const float*)d_in[7];
  const int* ballot   = (const int*)d_in[8];
  const int* contest  = (const int*)d_in[9];
  float* out = (float*)d_out;

  char* ws = (char*)d_ws;
  unsigned short* A   = (unsigned short*)(ws);                 //  67108864 B
  unsigned short* W0t = (unsigned short*)(ws + 67108864);      //  16777216 B
  unsigned short* h0  = (unsigned short*)(ws + 83886080);      //  33554432 B
  unsigned short* W1t = (unsigned short*)(ws + 117440512);     //   4194304 B
  unsigned short* h1  = (unsigned short*)(ws + 121634816);     //  16777216 B
  // total 138412032 B

  dim3 blk(256);
  // W0 [4096][2048] -> W0t [2048][4096]
  transpose_cvt<<<dim3(H0D / 32, KDIM / 32, 1), blk, 0, stream>>>(W0, W0t, KDIM, H0D);
  // W1 [2048][1024] -> W1t [1024][2048]
  transpose_cvt<<<dim3(H1D / 32, H0D / 32, 1), blk, 0, stream>>>(W1, W1t, H0D, H1D);
  build_A<<<dim3(B_SZ * 512 / 256), blk, 0, stream>>>(inputs, emb, ballot, contest, A);
  // GEMM1: [8192 x 4096] x [2048 x 4096]^T, 128x256 tiles -> 64*8 = 512 blocks
  gemm_nt_pipe<128, 256, 1, 4><<<dim3(512), blk, 0, stream>>>(
      A, W0t, b0, h0, KDIM, H0D, H0D / 256);
  // GEMM2: [8192 x 2048] x [1024 x 2048]^T, 128x128 tiles -> 64*8 = 512 blocks
  gemm_nt_pipe<128, 128, 2, 2><<<dim3(512), blk, 0, stream>>>(
      h0, W1t, b1, h1, H0D, H1D, H1D / 128);
  // routed head: 64 experts x 4 range-quarters = 256 blocks
  expert_head_bucketed<<<dim3(256), blk, 0, stream>>>(h1, We, be, ballot, contest, out);
}

// Round 5
// 288.740 us; speedup vs baseline: 1.0639x; 1.0639x over previous
//
#include <hip/hip_runtime.h>
#include <math.h>

typedef __attribute__((ext_vector_type(8))) short short8;
typedef __attribute__((ext_vector_type(4))) float f32x4;

#define B_SZ 8192
#define D_INN 4000
#define EMBD 96
#define H0D 2048
#define H1D 1024
#define KDIM 4096  // EMB + D_IN

__device__ __forceinline__ unsigned short f2bf(float f) {
  union { float f; unsigned u; } v; v.f = f;
  unsigned r = v.u + 0x7FFFu + ((v.u >> 16) & 1u);
  return (unsigned short)(r >> 16);
}
__device__ __forceinline__ float bf2f(unsigned short h) {
  union { unsigned u; float f; } v; v.u = ((unsigned)h) << 16;
  return v.f;
}
__device__ __forceinline__ void gld_lds16(const void* g, void* l) {
  __builtin_amdgcn_global_load_lds(
      (const __attribute__((address_space(1))) unsigned int*)g,
      (__attribute__((address_space(3))) unsigned int*)l, 16, 0, 0);
}

// ---- transpose + fp32->bf16 convert: out[c][r] = bf16(in[r][c]) ----
__global__ __launch_bounds__(256) void transpose_cvt(
    const float* __restrict__ in, unsigned short* __restrict__ out, int R, int C) {
  __shared__ float tile[32][33];
  int c0 = blockIdx.x * 32, r0 = blockIdx.y * 32;
  int tc = threadIdx.x & 31, tr = threadIdx.x >> 5;
#pragma unroll
  for (int i = 0; i < 4; ++i) {
    int r = tr + i * 8;
    tile[r][tc] = in[(size_t)(r0 + r) * C + (c0 + tc)];
  }
  __syncthreads();
#pragma unroll
  for (int i = 0; i < 4; ++i) {
    int rr = tr + i * 8;
    out[(size_t)(c0 + rr) * R + (r0 + tc)] = f2bf(tile[tc][rr]);
  }
}

// ---- build A = [emb_gather | inputs] in bf16, vectorized 8-wide ----
__global__ __launch_bounds__(256) void build_A(
    const float* __restrict__ inputs, const float* __restrict__ emb,
    const int* __restrict__ ballot, const int* __restrict__ contest,
    unsigned short* __restrict__ A) {
  int gid = blockIdx.x * 256 + threadIdx.x;   // chunk of 8 elems
  int b = gid >> 9, c = gid & 511;            // 512 chunks per row of 4096
  const float* src;
  if (c < EMBD / 8) {
    int e = ballot[b] * 8 + contest[b];
    src = emb + (size_t)e * EMBD + c * 8;
  } else {
    src = inputs + (size_t)b * D_INN + (c - EMBD / 8) * 8;
  }
  float4 v0 = *(const float4*)src;
  float4 v1 = *(const float4*)(src + 4);
  unsigned short r[8];
  r[0] = f2bf(v0.x); r[1] = f2bf(v0.y); r[2] = f2bf(v0.z); r[3] = f2bf(v0.w);
  r[4] = f2bf(v1.x); r[5] = f2bf(v1.y); r[6] = f2bf(v1.z); r[7] = f2bf(v1.w);
  *reinterpret_cast<short8*>(A + (size_t)b * KDIM + c * 8) =
      *reinterpret_cast<const short8*>(r);
}

#define BARRIER() __builtin_amdgcn_s_barrier()
#define LGKM0() do { asm volatile("s_waitcnt lgkmcnt(0)" ::: "memory"); \
                     __builtin_amdgcn_sched_barrier(0); } while (0)

// ---- 8-phase 256x256 NT bf16 GEMM (m201 schedule, plain HIP port) ----
// BK=64, 8 waves = 2(M) x 4(N), 512 threads. LDS 128 KB:
//   A: [2 buf][2 half=128 rows][128B rows] at 0;  B: same at 65536.
// Per K-tile, 4 phases, quadrant order (0,0),(0,1),(1,1),(1,0); per phase
// {ds_read frag subtile || stage 1 half-tile} -> barrier -> lgkm(0) ->
// setprio -> 16 MFMA -> barrier.  vmcnt(4) once per tile (2 half-tiles
// = 4 loads stay in flight; never 0 mid-loop).
// Stage schedule: ph0:A1(t+1) ph1:B0(t+1) ph2:B1(t+2) ph3:A0(t+2).
// RACE FIX (round 4 -> 5): phase 3 issues ZERO ds_reads. The nh=0 B
// fragments are HELD in registers from phase 0, because ph2's B1(t+2)
// stage overwrites LDS B-half-1 of the CURRENT buf, which waves wn>=2
// would hit on any phase-3 B read (that was the round-4 corruption).
// With no ph3 reads: B1 overwrite (ph2) — B reads end at ph1; A0
// overwrite (ph3) — A reads end at ph2; both safe behind phase barriers.
// Swizzle: LDS 16B slot' = slot ^ (row&7): pre-swizzled global source
// (linear gld_lds dest) + swizzled ds_read -> max 2-way (free).
__global__ __launch_bounds__(512, 2) void gemm_nt_8ph(
    const unsigned short* __restrict__ A, const unsigned short* __restrict__ Bt,
    const float* __restrict__ bias, unsigned short* __restrict__ C,
    int K, int N, int NBN) {
  __shared__ char lds[131072];
  const int tid = threadIdx.x;
  const int w = tid >> 6, l = tid & 63;
  const int lr = l & 15, kg = l >> 4;
  const int wm = w >> 2, wn = w & 3;

  int swz = (blockIdx.x & 7) * ((int)gridDim.x >> 3) + ((int)blockIdx.x >> 3);
  const int bm = swz / NBN, bn = swz - bm * NBN;
  const int NT = K >> 6;

  // staging: thread covers LDS positions p = w*64+l and p+512 of a half-tile
  const int row0 = w * 8 + (l >> 3);                     // 0..63 (+64 second)
  const int ss8 = ((l & 7) ^ ((l >> 3) & 7)) * 8;        // pre-swizzled slot
  const unsigned short* gA[2] = {
      A + (size_t)(bm * 256 + row0) * K + ss8,
      A + (size_t)(bm * 256 + 128 + row0) * K + ss8 };
  const unsigned short* gB[2] = {
      Bt + (size_t)(bn * 256 + row0) * K + ss8,
      Bt + (size_t)(bn * 256 + 128 + row0) * K + ss8 };

  auto stage = [&](const unsigned short* gbase, int region, int h, int buf, int t) {
    char* d = lds + region * 65536 + buf * 32768 + h * 16384 + w * 1024;
    const unsigned short* s = gbase + (size_t)t * 64;
    gld_lds16(s, d);
    gld_lds16(s + (size_t)64 * K, d + 8192);
  };

  const int lswz = lr & 7;
  // A frag: half = wm; local row = mh*64 + mi*16 + lr
  auto rdA = [&](int buf, int mh, int mi, int kk) -> short8 {
    const char* p = lds + buf * 32768 + wm * 16384 +
        (mh * 64 + mi * 16 + lr) * 128 + ((((kk << 2) | kg)) ^ lswz) * 16;
    return *(const short8*)p;
  };
  // B frag: half = wn>>1; local row = (wn&1)*64 + ni*16 + lr
  auto rdB = [&](int buf, int nh, int j, int kk) -> short8 {
    const char* p = lds + 65536 + buf * 32768 + (wn >> 1) * 16384 +
        ((wn & 1) * 64 + (nh * 2 + j) * 16 + lr) * 128 +
        ((((kk << 2) | kg)) ^ lswz) * 16;
    return *(const short8*)p;
  };

  f32x4 acc[8][4] = {};

  // prologue (steady-state issue order): B1(0) A0(0) A1(0) B0(0) B1(1) A0(1)
  stage(gB[1], 1, 1, 0, 0); stage(gA[0], 0, 0, 0, 0);
  stage(gA[1], 0, 1, 0, 0); stage(gB[0], 1, 0, 0, 0);
  stage(gB[1], 1, 1, 1, 1); stage(gA[0], 0, 0, 1, 1);
  asm volatile("s_waitcnt vmcnt(4)" ::: "memory");   // tile 0 landed
  BARRIER();
  __builtin_amdgcn_sched_barrier(0);

  for (int t = 0; t < NT; ++t) {
    const int buf = t & 1;
    short8 a[4][2], a2[4][2], b[2][2], b2[2][2];

    // ---- phase 0: read A[mh=0] (8) + B[nh=0] (4); MFMA Q(0,0) ----
#pragma unroll
    for (int mi = 0; mi < 4; ++mi)
#pragma unroll
      for (int kk = 0; kk < 2; ++kk) a[mi][kk] = rdA(buf, 0, mi, kk);
#pragma unroll
    for (int j = 0; j < 2; ++j)
#pragma unroll
      for (int kk = 0; kk < 2; ++kk) b[j][kk] = rdB(buf, 0, j, kk);
    if (t + 1 < NT) stage(gA[1], 0, 1, (t + 1) & 1, t + 1);
    BARRIER(); LGKM0();
    __builtin_amdgcn_s_setprio(1);
#pragma unroll
    for (int mi = 0; mi < 4; ++mi)
#pragma unroll
      for (int j = 0; j < 2; ++j)
#pragma unroll
        for (int kk = 0; kk < 2; ++kk)
          acc[mi][j] = __builtin_amdgcn_mfma_f32_16x16x32_bf16(
              a[mi][kk], b[j][kk], acc[mi][j], 0, 0, 0);
    __builtin_amdgcn_s_setprio(0);
    __builtin_amdgcn_sched_barrier(0);
    BARRIER();

    // ---- phase 1: read B[nh=1] (4); MFMA Q(0,1) (a held) ----
#pragma unroll
    for (int j = 0; j < 2; ++j)
#pragma unroll
      for (int kk = 0; kk < 2; ++kk) b2[j][kk] = rdB(buf, 1, j, kk);
    if (t + 1 < NT) stage(gB[0], 1, 0, (t + 1) & 1, t + 1);
    BARRIER(); LGKM0();
    __builtin_amdgcn_s_setprio(1);
#pragma unroll
    for (int mi = 0; mi < 4; ++mi)
#pragma unroll
      for (int j = 0; j < 2; ++j)
#pragma unroll
        for (int kk = 0; kk < 2; ++kk)
          acc[mi][2 + j] = __builtin_amdgcn_mfma_f32_16x16x32_bf16(
              a[mi][kk], b2[j][kk], acc[mi][2 + j], 0, 0, 0);
    __builtin_amdgcn_s_setprio(0);
    __builtin_amdgcn_sched_barrier(0);
    BARRIER();

    // ---- phase 2: read A[mh=1] (8); MFMA Q(1,1) (b2 held) ----
#pragma unroll
    for (int mi = 0; mi < 4; ++mi)
#pragma unroll
      for (int kk = 0; kk < 2; ++kk) a2[mi][kk] = rdA(buf, 1, mi, kk);
    if (t + 2 < NT) stage(gB[1], 1, 1, buf, t + 2);
    BARRIER(); LGKM0();
    __builtin_amdgcn_s_setprio(1);
#pragma unroll
    for (int mi = 0; mi < 4; ++mi)
#pragma unroll
      for (int j = 0; j < 2; ++j)
#pragma unroll
        for (int kk = 0; kk < 2; ++kk)
          acc[4 + mi][2 + j] = __builtin_amdgcn_mfma_f32_16x16x32_bf16(
              a2[mi][kk], b2[j][kk], acc[4 + mi][2 + j], 0, 0, 0);
    __builtin_amdgcn_s_setprio(0);
    __builtin_amdgcn_sched_barrier(0);
    BARRIER();

    // ---- phase 3: NO LDS reads; MFMA Q(1,0) (a2 + held b) ----
    if (t + 2 < NT) stage(gA[0], 0, 0, buf, t + 2);
    __builtin_amdgcn_s_setprio(1);
#pragma unroll
    for (int mi = 0; mi < 4; ++mi)
#pragma unroll
      for (int j = 0; j < 2; ++j)
#pragma unroll
        for (int kk = 0; kk < 2; ++kk)
          acc[4 + mi][j] = __builtin_amdgcn_mfma_f32_16x16x32_bf16(
              a2[mi][kk], b[j][kk], acc[4 + mi][j], 0, 0, 0);
    __builtin_amdgcn_s_setprio(0);
    __builtin_amdgcn_sched_barrier(0);
    if (t + 1 < NT) {
      if (t + 2 < NT) asm volatile("s_waitcnt vmcnt(4)" ::: "memory");
      else            asm volatile("s_waitcnt vmcnt(0)" ::: "memory");
      BARRIER();
    }
    __builtin_amdgcn_sched_barrier(0);
  }

  // epilogue: bias + relu + bf16 store.  D: col=lane&15, row=(lane>>4)*4+j
#pragma unroll
  for (int mi = 0; mi < 8; ++mi) {
    const int row0w = bm * 256 + wm * 128 + mi * 16 + kg * 4;
#pragma unroll
    for (int ni = 0; ni < 4; ++ni) {
      const int col = bn * 256 + wn * 64 + ni * 16 + lr;
      const float bv = bias[col];
#pragma unroll
      for (int j = 0; j < 4; ++j) {
        float v = acc[mi][ni][j] + bv;
        v = v > 0.f ? v : 0.f;
        C[(size_t)(row0w + j) * N + col] = f2bf(v);
      }
    }
  }
}

// ---- round-2 2-phase ring-3 GEMM (known-good) for GEMM2 ----
template <int MREP>
__global__ __launch_bounds__(512, 2) void gemm_nt_2ph(
    const unsigned short* __restrict__ A, const unsigned short* __restrict__ Bt,
    const float* __restrict__ bias, unsigned short* __restrict__ C,
    int K, int N, int NBN) {
  constexpr int BM  = MREP * 32;
  constexpr int AI  = MREP / 4;
  constexpr int ASH = BM * 32;
  constexpr int MH  = MREP / 2;
  __shared__ unsigned short lds[3 * ASH + 3 * 8192];

  const int tid = threadIdx.x;
  const int w = tid >> 6, l = tid & 63;
  const int lr = l & 15, kg = l >> 4;
  const int wm = w >> 2, wn = w & 3;

  int swz = (blockIdx.x & 7) * ((int)gridDim.x >> 3) + ((int)blockIdx.x >> 3);
  const int bm = swz / NBN, bn = swz - bm * NBN;
  const int NT = K >> 5;

  const int rg = l >> 2;
  const int sl = ((l & 3) ^ ((l >> 3) & 3)) * 8;
  const unsigned short* ga[AI];
#pragma unroll
  for (int i = 0; i < AI; ++i)
    ga[i] = A + (size_t)(bm * BM + (i * 8 + w) * 16 + rg) * K + sl;
  const unsigned short* gb0 = Bt + (size_t)(bn * 256 + w * 16 + rg) * K + sl;
  const unsigned short* gb1 = gb0 + (size_t)128 * K;

  const int xo = (kg ^ ((lr >> 1) & 3)) << 4;
  const int aoff = (wm * (MREP * 16) + lr) * 64 + xo;
  const int boff = (wn * 64 + lr) * 64 + xo;

  f32x4 acc[MREP][4] = {};

  auto stageA = [&](int t, int rbuf) {
    unsigned short* la = lds + rbuf * ASH + w * 512;
    const int ko = t * 32;
#pragma unroll
    for (int i = 0; i < AI; ++i) gld_lds16(ga[i] + ko, la + i * 4096);
  };
  auto stageB = [&](int t, int rbuf) {
    unsigned short* lb = lds + 3 * ASH + rbuf * 8192 + w * 512;
    const int ko = t * 32;
    gld_lds16(gb0 + ko, lb);
    gld_lds16(gb1 + ko, lb + 4096);
  };

#define WAIT_VM_STEADY() do { \
    if constexpr (AI == 2) asm volatile("s_waitcnt vmcnt(4)" ::: "memory"); \
    else                   asm volatile("s_waitcnt vmcnt(3)" ::: "memory"); \
  } while (0)

  stageA(0, 0); stageB(0, 0);
  stageA(1, 1); stageB(1, 1);
  WAIT_VM_STEADY();
  BARRIER();

  int rb = 0;
  for (int t = 0; t < NT; ++t) {
    int rb2 = rb + 2; if (rb2 >= 3) rb2 -= 3;
    const char* pa = (const char*)lds + rb * (ASH * 2) + aoff;
    const char* pb = (const char*)lds + 3 * (ASH * 2) + rb * 16384 + boff;

    short8 a0[MH], bfr[4];
#pragma unroll
    for (int mi = 0; mi < MH; ++mi) a0[mi] = *(const short8*)(pa + mi * 1024);
#pragma unroll
    for (int ni = 0; ni < 4; ++ni)  bfr[ni] = *(const short8*)(pb + ni * 1024);
    if (t + 2 < NT) stageA(t + 2, rb2);
    asm volatile("s_waitcnt lgkmcnt(0)" ::: "memory");
    BARRIER();
    __builtin_amdgcn_s_setprio(1);
#pragma unroll
    for (int mi = 0; mi < MH; ++mi)
#pragma unroll
      for (int ni = 0; ni < 4; ++ni)
        acc[mi][ni] = __builtin_amdgcn_mfma_f32_16x16x32_bf16(
            a0[mi], bfr[ni], acc[mi][ni], 0, 0, 0);
    __builtin_amdgcn_s_setprio(0);

    short8 a1[MH];
#pragma unroll
    for (int mi = 0; mi < MH; ++mi) a1[mi] = *(const short8*)(pa + (MH + mi) * 1024);
    if (t + 2 < NT) {
      stageB(t + 2, rb2);
      asm volatile("s_waitcnt lgkmcnt(0)" ::: "memory");
      WAIT_VM_STEADY();
      BARRIER();
    } else if (t + 1 < NT) {
      asm volatile("s_waitcnt lgkmcnt(0)" ::: "memory");
      asm volatile("s_waitcnt vmcnt(0)" ::: "memory");
      BARRIER();
    } else {
      asm volatile("s_waitcnt lgkmcnt(0)" ::: "memory");
    }
    __builtin_amdgcn_s_setprio(1);
#pragma unroll
    for (int mi = 0; mi < MH; ++mi)
#pragma unroll
      for (int ni = 0; ni < 4; ++ni)
        acc[MH + mi][ni] = __builtin_amdgcn_mfma_f32_16x16x32_bf16(
            a1[mi], bfr[ni], acc[MH + mi][ni], 0, 0, 0);
    __builtin_amdgcn_s_setprio(0);

    rb = rb + 1; if (rb >= 3) rb = 0;
  }

#pragma unroll
  for (int mi = 0; mi < MREP; ++mi) {
    const int row0 = bm * BM + wm * (MREP * 16) + mi * 16 + kg * 4;
#pragma unroll
    for (int ni = 0; ni < 4; ++ni) {
      const int col = bn * 256 + wn * 64 + ni * 16 + lr;
      const float bv = bias[col];
#pragma unroll
      for (int j = 0; j < 4; ++j) {
        float v = acc[mi][ni][j] + bv;
        v = v > 0.f ? v : 0.f;
        C[(size_t)(row0 + j) * N + col] = f2bf(v);
      }
    }
  }
#undef WAIT_VM_STEADY
}

// ---- routed expert head, bucketed: 64 experts x 4 sample-range quarters ----
__global__ __launch_bounds__(256) void expert_head_bucketed(
    const unsigned short* __restrict__ h1, const float* __restrict__ We,
    const float* __restrict__ be, const int* __restrict__ ballot,
    const int* __restrict__ contest, float* __restrict__ out) {
  const int e = blockIdx.x >> 2, q = blockIdx.x & 3;
  __shared__ unsigned short sidx[2048];
  __shared__ int scnt;
  __shared__ unsigned short sh1[32][1032];
  if (threadIdx.x == 0) scnt = 0;
  __syncthreads();
  const int base = q * 2048;
  for (int i = threadIdx.x; i < 2048; i += 256) {
    int s = base + i;
    if (ballot[s] * 8 + contest[s] == e)
      sidx[atomicAdd(&scnt, 1)] = (unsigned short)s;
  }
  __syncthreads();
  const int cnt = scnt;
  const int so = threadIdx.x >> 3;
  const int oq = threadIdx.x & 7;
  const float4* We4 = (const float4*)(We + (size_t)e * H1D * 32);
  for (int c0 = 0; c0 < cnt; c0 += 32) {
    const int ns = min(32, cnt - c0);
    __syncthreads();
    for (int t = threadIdx.x; t < ns * 128; t += 256) {
      int r = t >> 7, cc = (t & 127) * 8;
      *(short8*)&sh1[r][cc] =
          *(const short8*)&h1[(size_t)sidx[c0 + r] * H1D + cc];
    }
    __syncthreads();
    if (so < ns) {
      const int s = sidx[c0 + so];
      float ax = 0.f, ay = 0.f, az = 0.f, aw = 0.f;
#pragma unroll 8
      for (int d = 0; d < H1D; ++d) {
        float h = bf2f(sh1[so][d]);
        float4 wv = We4[d * 8 + oq];
        ax = fmaf(h, wv.x, ax); ay = fmaf(h, wv.y, ay);
        az = fmaf(h, wv.z, az); aw = fmaf(h, wv.w, aw);
      }
      float4 bb = *(const float4*)&be[e * 32 + oq * 4];
      float4 r;
      r.x = 1.f / (1.f + expf(-(ax + bb.x)));
      r.y = 1.f / (1.f + expf(-(ay + bb.y)));
      r.z = 1.f / (1.f + expf(-(az + bb.z)));
      r.w = 1.f / (1.f + expf(-(aw + bb.w)));
      *(float4*)&out[(size_t)s * 32 + oq * 4] = r;
    }
  }
}

extern "C" void kernel_launch(void* const* d_in, const int* in_sizes, int n_in,
                              void* d_out, int out_size, void* d_ws, size_t ws_size,
                              hipStream_t stream) {
  const float* inputs = (const float*)d_in[0];
  const float* emb    = (const float*)d_in[1];
  const float* W0     = (const float*)d_in[2];
  const float* b0     = (const float*)d_in[3];
  const float* W1     = (const float*)d_in[4];
  const float* b1     = (const float*)d_in[5];
  const float* We     = (const float*)d_in[6];
  const float* be     = (const float*)d_in[7];
  const int* ballot   = (const int*)d_in[8];
  const int* contest  = (const int*)d_in[9];
  float* out = (float*)d_out;

  char* ws = (char*)d_ws;
  unsigned short* A   = (unsigned short*)(ws);                 //  67108864 B
  unsigned short* W0t = (unsigned short*)(ws + 67108864);      //  16777216 B
  unsigned short* h0  = (unsigned short*)(ws + 83886080);      //  33554432 B
  unsigned short* W1t = (unsigned short*)(ws + 117440512);     //   4194304 B
  unsigned short* h1  = (unsigned short*)(ws + 121634816);     //  16777216 B
  // total 138412032 B

  dim3 blk(256);
  transpose_cvt<<<dim3(H0D / 32, KDIM / 32, 1), blk, 0, stream>>>(W0, W0t, KDIM, H0D);
  transpose_cvt<<<dim3(H1D / 32, H0D / 32, 1), blk, 0, stream>>>(W1, W1t, H0D, H1D);
  build_A<<<dim3(B_SZ * 512 / 256), blk, 0, stream>>>(inputs, emb, ballot, contest, A);
  // GEMM1: 256x256 tiles -> 32*8 = 256 blocks (1/CU), 8-phase schedule
  gemm_nt_8ph<<<dim3(256), dim3(512), 0, stream>>>(A, W0t, b0, h0, KDIM, H0D, H0D / 256);
  // GEMM2: 128x256 tiles -> 64*4 = 256 blocks, round-2 2-phase schedule
  gemm_nt_2ph<4><<<dim3(256), dim3(512), 0, stream>>>(h0, W1t, b1, h1, H0D, H1D, H1D / 256);
  expert_head_bucketed<<<dim3(256), blk, 0, stream>>>(h1, We, be, ballot, contest, out);
}